// Round 1
// baseline (301.720 us; speedup 1.0000x reference)
//
#include <hip/hip_runtime.h>
#include <hip/hip_bf16.h>

#define N_NODES 8192
#define F_IN    512
#define F_HID   256
#define ALPHA   0.2f
#define MAXDEG  64

// ---------------------------------------------------------------------------
// Kernel 1: build CSR-style neighbor lists from dense adjacency.
// One wave (64 lanes) per row; deterministic ballot+prefix compaction.
// ---------------------------------------------------------------------------
__global__ void build_csr(const float* __restrict__ adj,
                          int* __restrict__ cols, int* __restrict__ cnt) {
    const int wavesPerBlock = blockDim.x / 64;
    const int row = blockIdx.x * wavesPerBlock + (threadIdx.x / 64);
    const int lane = threadIdx.x & 63;
    if (row >= N_NODES) return;
    const float* arow = adj + (size_t)row * N_NODES;
    int* crow = cols + (size_t)row * MAXDEG;
    int count = 0;
    for (int base = 0; base < N_NODES; base += 64) {
        float v = arow[base + lane];
        bool pred = v > 0.0f;
        unsigned long long m = __ballot(pred);
        if (pred) {
            int pos = count + __popcll(m & ((1ULL << lane) - 1ULL));
            if (pos < MAXDEG) crow[pos] = base + lane;
        }
        count += __popcll(m);
    }
    if (lane == 0) cnt[row] = count > MAXDEG ? MAXDEG : count;
}

// ---------------------------------------------------------------------------
// Kernel 2: generic fp32 tiled GEMM  C[M,Nn] = A[M,K] @ B[K,Nn] (row-major).
// 64x64 tile, BK=16, 256 threads, 4x4 per thread.
// ---------------------------------------------------------------------------
__global__ void gemm_f32(const float* __restrict__ A, const float* __restrict__ B,
                         float* __restrict__ C, int M, int K, int Nn) {
    const int BM = 64, BN = 64, BK = 16, TM = 4, TN = 4;
    __shared__ float As[BK][BM + 1];
    __shared__ float Bs[BK][BN + 1];
    const int tid = threadIdx.x;
    const int tx = tid % 16, ty = tid / 16;
    const int brow = blockIdx.y * BM;
    const int bcol = blockIdx.x * BN;
    float acc[TM][TN] = {};
    for (int k0 = 0; k0 < K; k0 += BK) {
        #pragma unroll
        for (int i = tid; i < BM * BK; i += 256) {
            int r = i / BK, c = i % BK;
            As[c][r] = A[(size_t)(brow + r) * K + (k0 + c)];
        }
        #pragma unroll
        for (int i = tid; i < BK * BN; i += 256) {
            int r = i / BN, c = i % BN;
            Bs[r][c] = B[(size_t)(k0 + r) * Nn + (bcol + c)];
        }
        __syncthreads();
        #pragma unroll
        for (int kk = 0; kk < BK; ++kk) {
            float av[TM], bv[TN];
            #pragma unroll
            for (int m = 0; m < TM; ++m) av[m] = As[kk][ty * TM + m];
            #pragma unroll
            for (int n = 0; n < TN; ++n) bv[n] = Bs[kk][tx * TN + n];
            #pragma unroll
            for (int m = 0; m < TM; ++m)
                #pragma unroll
                for (int n = 0; n < TN; ++n)
                    acc[m][n] += av[m] * bv[n];
        }
        __syncthreads();
    }
    #pragma unroll
    for (int m = 0; m < TM; ++m)
        #pragma unroll
        for (int n = 0; n < TN; ++n)
            C[(size_t)(brow + ty * TM + m) * Nn + (bcol + tx * TN + n)] = acc[m][n];
}

// ---------------------------------------------------------------------------
// Kernel 3: s[i] = Wh[i,:] . a[0:F],  t[i] = Wh[i,:] . a[F:2F]
// ---------------------------------------------------------------------------
__global__ void compute_st(const float* __restrict__ Wh, const float* __restrict__ a,
                           float* __restrict__ s, float* __restrict__ t, int F) {
    const int row = blockIdx.x;
    const int tid = threadIdx.x;
    float ss = 0.0f, tt = 0.0f;
    for (int f = tid; f < F; f += 256) {
        float w = Wh[(size_t)row * F + f];
        ss += w * a[f];
        tt += w * a[F + f];
    }
    __shared__ float rs[256], rt[256];
    rs[tid] = ss; rt[tid] = tt;
    __syncthreads();
    for (int off = 128; off > 0; off >>= 1) {
        if (tid < off) { rs[tid] += rs[tid + off]; rt[tid] += rt[tid + off]; }
        __syncthreads();
    }
    if (tid == 0) { s[row] = rs[0]; t[row] = rt[0]; }
}

// ---------------------------------------------------------------------------
// Kernel 4: per-row masked softmax over neighbors + aggregation + ELU.
// out[i,:] = elu( sum_d p_d * Wh[j_d,:] ),  p = softmax(leakyrelu(s_i + t_j))
// ---------------------------------------------------------------------------
__global__ void aggregate(const float* __restrict__ Wh,
                          const int* __restrict__ cols, const int* __restrict__ cnt,
                          const float* __restrict__ s, const float* __restrict__ t,
                          float* __restrict__ out, int F) {
    const int row = blockIdx.x;
    const int tid = threadIdx.x;
    const int deg = cnt[row];
    __shared__ float p[MAXDEG];
    __shared__ int jidx[MAXDEG];
    if (tid < 64) {
        int j = -1;
        float ev = -1e30f;
        if (tid < deg) {
            j = cols[(size_t)row * MAXDEG + tid];
            float z = s[row] + t[j];
            ev = z > 0.0f ? z : ALPHA * z;
        }
        float m = ev;
        #pragma unroll
        for (int off = 32; off > 0; off >>= 1) m = fmaxf(m, __shfl_xor(m, off));
        float ex = (tid < deg) ? __expf(ev - m) : 0.0f;
        float sum = ex;
        #pragma unroll
        for (int off = 32; off > 0; off >>= 1) sum += __shfl_xor(sum, off);
        if (tid < deg) { p[tid] = ex / sum; jidx[tid] = j; }
    }
    __syncthreads();
    for (int f = tid; f < F; f += blockDim.x) {
        float acc = 0.0f;
        for (int d = 0; d < deg; ++d)
            acc += p[d] * Wh[(size_t)jidx[d] * F + f];
        out[(size_t)row * F + f] = acc > 0.0f ? acc : (__expf(acc) - 1.0f);
    }
}

// ---------------------------------------------------------------------------
extern "C" void kernel_launch(void* const* d_in, const int* in_sizes, int n_in,
                              void* d_out, int out_size, void* d_ws, size_t ws_size,
                              hipStream_t stream) {
    (void)in_sizes; (void)n_in; (void)out_size; (void)ws_size;
    const float* x   = (const float*)d_in[0];
    const float* adj = (const float*)d_in[1];
    const float* W1  = (const float*)d_in[2];
    const float* a1  = (const float*)d_in[3];
    const float* W2  = (const float*)d_in[4];
    const float* a2  = (const float*)d_in[5];

    float* dec = (float*)d_out;                         // [8192, 512]
    float* enc = dec + (size_t)N_NODES * F_IN;          // [8192, 256]

    // workspace layout
    int*   cols = (int*)d_ws;                           // 8192*64 ints
    int*   cnt  = cols + (size_t)N_NODES * MAXDEG;      // 8192 ints
    float* sbuf = (float*)(cnt + N_NODES);              // 8192
    float* tbuf = sbuf + N_NODES;                       // 8192
    float* Wh   = tbuf + N_NODES;                       // up to 8192*512 f32

    // 1. adjacency -> CSR (shared by both layers)
    build_csr<<<N_NODES / 4, 256, 0, stream>>>(adj, cols, cnt);

    // ---- layer 1 (encode): x[8192,512] @ W1[512,256] ----
    gemm_f32<<<dim3(F_HID / 64, N_NODES / 64), 256, 0, stream>>>(x, W1, Wh, N_NODES, F_IN, F_HID);
    compute_st<<<N_NODES, 256, 0, stream>>>(Wh, a1, sbuf, tbuf, F_HID);
    aggregate<<<N_NODES, 256, 0, stream>>>(Wh, cols, cnt, sbuf, tbuf, enc, F_HID);

    // ---- layer 2 (decode): enc[8192,256] @ W2[256,512] ----
    gemm_f32<<<dim3(F_IN / 64, N_NODES / 64), 256, 0, stream>>>(enc, W2, Wh, N_NODES, F_HID, F_IN);
    compute_st<<<N_NODES, 256, 0, stream>>>(Wh, a2, sbuf, tbuf, F_IN);
    aggregate<<<N_NODES, 256, 0, stream>>>(Wh, cols, cnt, sbuf, tbuf, dec, F_IN);
}

// Round 2
// 246.485 us; speedup vs baseline: 1.2241x; 1.2241x over previous
//
#include <hip/hip_runtime.h>
#include <hip/hip_bf16.h>

#define N_NODES 8192
#define F_IN    512
#define F_HID   256
#define ALPHA   0.2f
#define MAXDEG  64

using f32x4  = __attribute__((ext_vector_type(4))) float;
using bf16x8 = __attribute__((ext_vector_type(8))) short;

__device__ inline short f32_to_bf16_rne(float x) {
    unsigned u = __builtin_bit_cast(unsigned, x);
    unsigned r = (u + 0x7FFFu + ((u >> 16) & 1u)) >> 16;
    return (short)r;
}
__device__ inline float bf16_to_f32(short b) {
    unsigned u = ((unsigned)(unsigned short)b) << 16;
    return __builtin_bit_cast(float, u);
}

// ---------------------------------------------------------------------------
// Kernel 1: dense adjacency -> CSR neighbor lists. One wave per row,
// float4 loads (1KB/wave-instr), ballot x4 + prefix compaction (order kept).
// ---------------------------------------------------------------------------
__global__ void build_csr(const float* __restrict__ adj,
                          int* __restrict__ cols, int* __restrict__ cnt) {
    const int row  = blockIdx.x * (blockDim.x >> 6) + (threadIdx.x >> 6);
    const int lane = threadIdx.x & 63;
    const float4* arow = (const float4*)(adj + (size_t)row * N_NODES);
    int* crow = cols + (size_t)row * MAXDEG;
    int count = 0;
    const unsigned long long mlt = (1ULL << lane) - 1ULL;
    for (int base = 0; base < N_NODES; base += 256) {
        float4 v = arow[(base >> 2) + lane];
        unsigned long long b0 = __ballot(v.x > 0.0f);
        unsigned long long b1 = __ballot(v.y > 0.0f);
        unsigned long long b2 = __ballot(v.z > 0.0f);
        unsigned long long b3 = __ballot(v.w > 0.0f);
        int o = count + __popcll(b0 & mlt) + __popcll(b1 & mlt)
                      + __popcll(b2 & mlt) + __popcll(b3 & mlt);
        int c0 = base + (lane << 2);
        if (v.x > 0.0f) { if (o < MAXDEG) crow[o] = c0;     o++; }
        if (v.y > 0.0f) { if (o < MAXDEG) crow[o] = c0 + 1; o++; }
        if (v.z > 0.0f) { if (o < MAXDEG) crow[o] = c0 + 2; o++; }
        if (v.w > 0.0f) { if (o < MAXDEG) crow[o] = c0 + 3; o++; }
        count += __popcll(b0) + __popcll(b1) + __popcll(b2) + __popcll(b3);
    }
    if (lane == 0) cnt[row] = count > MAXDEG ? MAXDEG : count;
}

// ---------------------------------------------------------------------------
// Kernel 2: split W[K][Nn] (f32) into B^T bf16 blocks [Nn][3K] = [hi|hi|lo].
// Pairs with A' = [hi|lo|hi]: product = Ahi*Bhi + Alo*Bhi + Ahi*Blo.
// ---------------------------------------------------------------------------
__global__ void split_BT(const float* __restrict__ W, short* __restrict__ BT,
                         int K, int Nn) {
    int idx = blockIdx.x * blockDim.x + threadIdx.x;
    if (idx >= K * Nn) return;
    int k = idx / Nn, n = idx % Nn;
    float x = W[idx];
    short hi = f32_to_bf16_rne(x);
    short lo = f32_to_bf16_rne(x - bf16_to_f32(hi));
    size_t b = (size_t)n * (3 * K);
    BT[b + k]         = hi;
    BT[b + K + k]     = hi;
    BT[b + 2 * K + k] = lo;
}

// ---------------------------------------------------------------------------
// Kernel 3: split-bf16 MFMA GEMM. C[M][Nn] = A[M][KSRC](f32) @ W via
// logical K' = 3*KSRC. A converted hi/lo during LDS staging (mode by block).
// BM=128, BK=64, 256 threads = 4 waves (2x2), mfma_f32_16x16x32_bf16.
// A frag: row = lane&15, k = 8*(lane>>4)+j. C: col=lane&15, row=(lane>>4)*4+j.
// ---------------------------------------------------------------------------
template<int BN, int KSRC>
__global__ __launch_bounds__(256)
void gemm_split_bf16(const float* __restrict__ A, const short* __restrict__ BT,
                     float* __restrict__ C, int Nn) {
    const int BM = 128, BK = 64, LDT = 72;  // +8 bf16 pad: 2-way banks (free)
    const int NF = BN / 32;                 // 16-col frags per wave
    __shared__ short As[BM * LDT];
    __shared__ short Bs[BN * LDT];
    const int tid = threadIdx.x;
    const int wid = tid >> 6, lane = tid & 63;
    const int brow = blockIdx.y * BM;
    const int bcol = blockIdx.x * BN;
    const int wr = (wid >> 1) * 64;
    const int wc = (wid & 1) * (BN / 2);
    const int KP = 3 * KSRC;

    f32x4 acc[4][NF];
    #pragma unroll
    for (int m = 0; m < 4; ++m)
        #pragma unroll
        for (int n = 0; n < NF; ++n) acc[m][n] = f32x4{0.f, 0.f, 0.f, 0.f};

    for (int kt = 0; kt < KP / BK; ++kt) {
        const int klog = kt * BK;
        const int mode = klog / KSRC;   // 0:hi 1:lo 2:hi  (A-side)
        const int ksrc = klog % KSRC;
        // stage A (convert f32 -> bf16 hi/lo)
        #pragma unroll
        for (int i = 0; i < (BM * BK / 8) / 256; ++i) {
            int id = tid + i * 256;
            int r = id >> 3, kg = (id & 7) * 8;
            const float* src = A + (size_t)(brow + r) * KSRC + ksrc + kg;
            f32x4 x0 = *(const f32x4*)src;
            f32x4 x1 = *(const f32x4*)(src + 4);
            short v[8];
            #pragma unroll
            for (int j = 0; j < 8; ++j) {
                float x = (j < 4) ? x0[j] : x1[j - 4];
                short hi = f32_to_bf16_rne(x);
                if (mode == 1) hi = f32_to_bf16_rne(x - bf16_to_f32(hi));
                v[j] = hi;
            }
            *(bf16x8*)&As[r * LDT + kg] = *(const bf16x8*)v;
        }
        // stage B (already split bf16, [Nn][KP] row-major)
        #pragma unroll
        for (int i = 0; i < (BN * BK / 8) / 256; ++i) {
            int id = tid + i * 256;
            int r = id >> 3, kg = (id & 7) * 8;
            *(bf16x8*)&Bs[r * LDT + kg] =
                *(const bf16x8*)&BT[(size_t)(bcol + r) * KP + klog + kg];
        }
        __syncthreads();
        #pragma unroll
        for (int ks = 0; ks < 2; ++ks) {
            const int kb = ks * 32 + (lane >> 4) * 8;
            bf16x8 af[4], bfr[NF];
            #pragma unroll
            for (int m = 0; m < 4; ++m)
                af[m] = *(const bf16x8*)&As[(wr + m * 16 + (lane & 15)) * LDT + kb];
            #pragma unroll
            for (int n = 0; n < NF; ++n)
                bfr[n] = *(const bf16x8*)&Bs[(wc + n * 16 + (lane & 15)) * LDT + kb];
            #pragma unroll
            for (int m = 0; m < 4; ++m)
                #pragma unroll
                for (int n = 0; n < NF; ++n)
                    acc[m][n] = __builtin_amdgcn_mfma_f32_16x16x32_bf16(
                        af[m], bfr[n], acc[m][n], 0, 0, 0);
        }
        __syncthreads();
    }
    #pragma unroll
    for (int m = 0; m < 4; ++m)
        #pragma unroll
        for (int n = 0; n < NF; ++n) {
            int row = brow + wr + m * 16 + ((lane >> 4) << 2);
            int col = bcol + wc + n * 16 + (lane & 15);
            #pragma unroll
            for (int j = 0; j < 4; ++j)
                C[(size_t)(row + j) * Nn + col] = acc[m][n][j];
        }
}

// ---------------------------------------------------------------------------
// Kernel 4: s[i] = Wh[i,:].a[0:F], t[i] = Wh[i,:].a[F:2F]
// ---------------------------------------------------------------------------
__global__ void compute_st(const float* __restrict__ Wh, const float* __restrict__ a,
                           float* __restrict__ s, float* __restrict__ t, int F) {
    const int row = blockIdx.x;
    const int tid = threadIdx.x;
    float ss = 0.0f, tt = 0.0f;
    for (int f = tid; f < F; f += 256) {
        float w = Wh[(size_t)row * F + f];
        ss += w * a[f];
        tt += w * a[F + f];
    }
    __shared__ float rs[256], rt[256];
    rs[tid] = ss; rt[tid] = tt;
    __syncthreads();
    for (int off = 128; off > 0; off >>= 1) {
        if (tid < off) { rs[tid] += rs[tid + off]; rt[tid] += rt[tid + off]; }
        __syncthreads();
    }
    if (tid == 0) { s[row] = rs[0]; t[row] = rt[0]; }
}

// ---------------------------------------------------------------------------
// Kernel 5: masked row softmax over neighbors + aggregate + ELU.
// ---------------------------------------------------------------------------
__global__ void aggregate(const float* __restrict__ Wh,
                          const int* __restrict__ cols, const int* __restrict__ cnt,
                          const float* __restrict__ s, const float* __restrict__ t,
                          float* __restrict__ out, int F) {
    const int row = blockIdx.x;
    const int tid = threadIdx.x;
    const int deg = cnt[row];
    __shared__ float p[MAXDEG];
    __shared__ int jidx[MAXDEG];
    if (tid < 64) {
        int j = -1;
        float ev = -1e30f;
        if (tid < deg) {
            j = cols[(size_t)row * MAXDEG + tid];
            float z = s[row] + t[j];
            ev = z > 0.0f ? z : ALPHA * z;
        }
        float m = ev;
        #pragma unroll
        for (int off = 32; off > 0; off >>= 1) m = fmaxf(m, __shfl_xor(m, off));
        float ex = (tid < deg) ? __expf(ev - m) : 0.0f;
        float sum = ex;
        #pragma unroll
        for (int off = 32; off > 0; off >>= 1) sum += __shfl_xor(sum, off);
        if (tid < deg) { p[tid] = ex / sum; jidx[tid] = j; }
    }
    __syncthreads();
    for (int f = tid; f < F; f += blockDim.x) {
        float acc = 0.0f;
        for (int d = 0; d < deg; ++d)
            acc += p[d] * Wh[(size_t)jidx[d] * F + f];
        out[(size_t)row * F + f] = acc > 0.0f ? acc : (__expf(acc) - 1.0f);
    }
}

// ---------------------------------------------------------------------------
extern "C" void kernel_launch(void* const* d_in, const int* in_sizes, int n_in,
                              void* d_out, int out_size, void* d_ws, size_t ws_size,
                              hipStream_t stream) {
    (void)in_sizes; (void)n_in; (void)out_size; (void)ws_size;
    const float* x   = (const float*)d_in[0];
    const float* adj = (const float*)d_in[1];
    const float* W1  = (const float*)d_in[2];
    const float* a1  = (const float*)d_in[3];
    const float* W2  = (const float*)d_in[4];
    const float* a2  = (const float*)d_in[5];

    float* dec = (float*)d_out;                         // [8192, 512]
    float* enc = dec + (size_t)N_NODES * F_IN;          // [8192, 256]

    int*   cols = (int*)d_ws;                           // 8192*64
    int*   cnt  = cols + (size_t)N_NODES * MAXDEG;      // 8192
    float* sbuf = (float*)(cnt + N_NODES);              // 8192
    float* tbuf = sbuf + N_NODES;                       // 8192
    float* Wh1  = tbuf + N_NODES;                       // 8192*256 f32
    float* Wh2  = Wh1 + (size_t)N_NODES * F_HID;        // 8192*512 f32
    short* B1T  = (short*)(Wh2 + (size_t)N_NODES * F_IN); // 256 * 1536 bf16
    short* B2T  = B1T + (size_t)F_HID * 3 * F_IN;         // 512 * 768 bf16

    build_csr<<<N_NODES / 4, 256, 0, stream>>>(adj, cols, cnt);

    // ---- layer 1 (encode): x[8192,512] @ W1[512,256] ----
    split_BT<<<(F_IN * F_HID + 255) / 256, 256, 0, stream>>>(W1, B1T, F_IN, F_HID);
    gemm_split_bf16<64, F_IN><<<dim3(F_HID / 64, N_NODES / 128), 256, 0, stream>>>(x, B1T, Wh1, F_HID);
    compute_st<<<N_NODES, 256, 0, stream>>>(Wh1, a1, sbuf, tbuf, F_HID);
    aggregate<<<N_NODES, 256, 0, stream>>>(Wh1, cols, cnt, sbuf, tbuf, enc, F_HID);

    // ---- layer 2 (decode): enc[8192,256] @ W2[256,512] ----
    split_BT<<<(F_HID * F_IN + 255) / 256, 256, 0, stream>>>(W2, B2T, F_HID, F_IN);
    gemm_split_bf16<128, F_HID><<<dim3(F_IN / 128, N_NODES / 128), 256, 0, stream>>>(enc, B2T, Wh2, F_IN);
    compute_st<<<N_NODES, 256, 0, stream>>>(Wh2, a2, sbuf, tbuf, F_IN);
    aggregate<<<N_NODES, 256, 0, stream>>>(Wh2, cols, cnt, sbuf, tbuf, dec, F_IN);
}

// Round 3
// 149.566 us; speedup vs baseline: 2.0173x; 1.6480x over previous
//
#include <hip/hip_runtime.h>
#include <hip/hip_bf16.h>

#define N_NODES 8192
#define F_IN    512
#define F_HID   256
#define ALPHA   0.2f
#define MAXDEG  64

using f32x4 = __attribute__((ext_vector_type(4))) float;
using f16x8 = __attribute__((ext_vector_type(8))) _Float16;

// ---------------------------------------------------------------------------
// Kernel 1: dense adjacency -> CSR neighbor lists. One wave per row.
// ---------------------------------------------------------------------------
__global__ void build_csr(const float* __restrict__ adj,
                          int* __restrict__ cols, int* __restrict__ cnt) {
    const int row  = blockIdx.x * (blockDim.x >> 6) + (threadIdx.x >> 6);
    const int lane = threadIdx.x & 63;
    const float4* arow = (const float4*)(adj + (size_t)row * N_NODES);
    int* crow = cols + (size_t)row * MAXDEG;
    int count = 0;
    const unsigned long long mlt = (1ULL << lane) - 1ULL;
    for (int base = 0; base < N_NODES; base += 256) {
        float4 v = arow[(base >> 2) + lane];
        unsigned long long b0 = __ballot(v.x > 0.0f);
        unsigned long long b1 = __ballot(v.y > 0.0f);
        unsigned long long b2 = __ballot(v.z > 0.0f);
        unsigned long long b3 = __ballot(v.w > 0.0f);
        int o = count + __popcll(b0 & mlt) + __popcll(b1 & mlt)
                      + __popcll(b2 & mlt) + __popcll(b3 & mlt);
        int c0 = base + (lane << 2);
        if (v.x > 0.0f) { if (o < MAXDEG) crow[o] = c0;     o++; }
        if (v.y > 0.0f) { if (o < MAXDEG) crow[o] = c0 + 1; o++; }
        if (v.z > 0.0f) { if (o < MAXDEG) crow[o] = c0 + 2; o++; }
        if (v.w > 0.0f) { if (o < MAXDEG) crow[o] = c0 + 3; o++; }
        count += __popcll(b0) + __popcll(b1) + __popcll(b2) + __popcll(b3);
    }
    if (lane == 0) cnt[row] = count > MAXDEG ? MAXDEG : count;
}

// ---------------------------------------------------------------------------
// Kernel 2: x [8192,512] f32 -> fp16, 8 elems/thread.
// ---------------------------------------------------------------------------
__global__ void conv_x16(const float* __restrict__ x, _Float16* __restrict__ x16) {
    int id = blockIdx.x * blockDim.x + threadIdx.x;
    const f32x4* src = (const f32x4*)(x + (size_t)id * 8);
    f32x4 v0 = src[0], v1 = src[1];
    f16x8 o;
    #pragma unroll
    for (int j = 0; j < 4; ++j) { o[j] = (_Float16)v0[j]; o[4 + j] = (_Float16)v1[j]; }
    *(f16x8*)(x16 + (size_t)id * 8) = o;
}

// ---------------------------------------------------------------------------
// Kernel 3: W [K][N] f32 -> WT [N][K] fp16, 32x32 LDS tile transpose.
// One launch covers both layers (256 tile-blocks).
// ---------------------------------------------------------------------------
__global__ void conv_WT(const float* __restrict__ W1, const float* __restrict__ W2,
                        _Float16* __restrict__ W1T, _Float16* __restrict__ W2T) {
    int t = blockIdx.x;
    const float* W; _Float16* WT; int K, N, kt, nt;
    if (t < 128) { W = W1; WT = W1T; K = 512; N = 256; kt = t & 15; nt = t >> 4; }
    else { t -= 128; W = W2; WT = W2T; K = 256; N = 512; kt = t & 7; nt = t >> 3; }
    __shared__ float Ws[32][33];
    const int tx = threadIdx.x & 31, ty = threadIdx.x >> 5;  // 32 x 8
    #pragma unroll
    for (int i = 0; i < 4; ++i)
        Ws[ty + 8 * i][tx] = W[(size_t)(kt * 32 + ty + 8 * i) * N + nt * 32 + tx];
    __syncthreads();
    #pragma unroll
    for (int i = 0; i < 4; ++i)
        WT[(size_t)(nt * 32 + ty + 8 * i) * K + kt * 32 + tx] = (_Float16)Ws[tx][ty + 8 * i];
}

// ---------------------------------------------------------------------------
// Kernel 4: fp16 MFMA GEMM. C[M][Nn] f32 = A[M][K] fp16 @ BT[Nn][K] fp16.
// BM=BN=BK=64, 256 thr = 4 waves (2x2), wave tile 32x32, mfma 16x16x32_f16.
// LDS rows padded to 72 halfs (144B): frag reads are 2-way bank (free).
// ---------------------------------------------------------------------------
__global__ __launch_bounds__(256)
void gemm_f16(const _Float16* __restrict__ A, const _Float16* __restrict__ BT,
              float* __restrict__ C, int K, int Nn) {
    const int LDT = 72;
    __shared__ _Float16 As[64 * LDT];
    __shared__ _Float16 Bs[64 * LDT];
    const int tid = threadIdx.x;
    const int wid = tid >> 6, lane = tid & 63;
    const int brow = blockIdx.y * 64;
    const int bcol = blockIdx.x * 64;
    const int wr = (wid >> 1) * 32, wc = (wid & 1) * 32;
    const int sr = tid >> 3, skg = (tid & 7) * 8;   // staging coords (rows 0..31)

    f32x4 acc[2][2];
    #pragma unroll
    for (int m = 0; m < 2; ++m)
        #pragma unroll
        for (int n = 0; n < 2; ++n) acc[m][n] = f32x4{0.f, 0.f, 0.f, 0.f};

    for (int k0 = 0; k0 < K; k0 += 64) {
        #pragma unroll
        for (int i = 0; i < 2; ++i) {
            int r = sr + i * 32;
            *(f16x8*)&As[r * LDT + skg] = *(const f16x8*)&A[(size_t)(brow + r) * K + k0 + skg];
            *(f16x8*)&Bs[r * LDT + skg] = *(const f16x8*)&BT[(size_t)(bcol + r) * K + k0 + skg];
        }
        __syncthreads();
        #pragma unroll
        for (int ks = 0; ks < 2; ++ks) {
            const int kb = ks * 32 + (lane >> 4) * 8;
            f16x8 af[2], bfr[2];
            #pragma unroll
            for (int m = 0; m < 2; ++m)
                af[m] = *(const f16x8*)&As[(wr + m * 16 + (lane & 15)) * LDT + kb];
            #pragma unroll
            for (int n = 0; n < 2; ++n)
                bfr[n] = *(const f16x8*)&Bs[(wc + n * 16 + (lane & 15)) * LDT + kb];
            #pragma unroll
            for (int m = 0; m < 2; ++m)
                #pragma unroll
                for (int n = 0; n < 2; ++n)
                    acc[m][n] = __builtin_amdgcn_mfma_f32_16x16x32_f16(
                        af[m], bfr[n], acc[m][n], 0, 0, 0);
        }
        __syncthreads();
    }
    #pragma unroll
    for (int m = 0; m < 2; ++m)
        #pragma unroll
        for (int n = 0; n < 2; ++n) {
            int row = brow + wr + m * 16 + ((lane >> 4) << 2);
            int col = bcol + wc + n * 16 + (lane & 15);
            #pragma unroll
            for (int j = 0; j < 4; ++j)
                C[(size_t)(row + j) * Nn + col] = acc[m][n][j];
        }
}

// ---------------------------------------------------------------------------
// Kernel 5: s[i] = Wh[i,:].a[0:F], t[i] = Wh[i,:].a[F:2F]. Wave per row.
// ---------------------------------------------------------------------------
template<int F>
__global__ void compute_st(const float* __restrict__ Wh, const float* __restrict__ a,
                           float* __restrict__ s, float* __restrict__ t) {
    const int lane = threadIdx.x & 63;
    const int row = blockIdx.x * (blockDim.x >> 6) + (threadIdx.x >> 6);
    const f32x4* wr = (const f32x4*)(Wh + (size_t)row * F);
    const f32x4* av = (const f32x4*)a;
    float ss = 0.f, tt = 0.f;
    #pragma unroll
    for (int c = 0; c < F / 256; ++c) {
        f32x4 w = wr[c * 64 + lane];
        f32x4 a0 = av[c * 64 + lane];
        f32x4 a1 = av[F / 4 + c * 64 + lane];
        #pragma unroll
        for (int j = 0; j < 4; ++j) { ss += w[j] * a0[j]; tt += w[j] * a1[j]; }
    }
    #pragma unroll
    for (int off = 32; off > 0; off >>= 1) {
        ss += __shfl_xor(ss, off);
        tt += __shfl_xor(tt, off);
    }
    if (lane == 0) { s[row] = ss; t[row] = tt; }
}

// ---------------------------------------------------------------------------
// Kernel 6: masked softmax over neighbors + aggregate + ELU. Wave per row,
// f32x4 gathers. Optionally emits fp16 copy (next layer's GEMM input).
// ---------------------------------------------------------------------------
template<int F>
__global__ void aggregate(const float* __restrict__ Wh,
                          const int* __restrict__ cols, const int* __restrict__ cnt,
                          const float* __restrict__ s, const float* __restrict__ t,
                          float* __restrict__ out, _Float16* __restrict__ out16) {
    const int wid = threadIdx.x >> 6, lane = threadIdx.x & 63;
    const int row = blockIdx.x * 4 + wid;
    const int deg = cnt[row];
    __shared__ float pS[4][64];
    __shared__ int jS[4][64];
    int j = 0;
    float ev = -1e30f;
    if (lane < deg) {
        j = cols[(size_t)row * MAXDEG + lane];
        float z = s[row] + t[j];
        ev = z > 0.0f ? z : ALPHA * z;
    }
    float m = ev;
    #pragma unroll
    for (int off = 32; off > 0; off >>= 1) m = fmaxf(m, __shfl_xor(m, off));
    float ex = (lane < deg) ? __expf(ev - m) : 0.0f;
    float sum = ex;
    #pragma unroll
    for (int off = 32; off > 0; off >>= 1) sum += __shfl_xor(sum, off);
    pS[wid][lane] = ex / sum;
    jS[wid][lane] = j;
    __syncthreads();

    f32x4 acc[F / 256];
    #pragma unroll
    for (int c = 0; c < F / 256; ++c) acc[c] = f32x4{0.f, 0.f, 0.f, 0.f};
    for (int d = 0; d < deg; ++d) {
        float p = pS[wid][d];
        const f32x4* wr = (const f32x4*)(Wh + (size_t)jS[wid][d] * F);
        #pragma unroll
        for (int c = 0; c < F / 256; ++c) {
            f32x4 w = wr[c * 64 + lane];
            #pragma unroll
            for (int jj = 0; jj < 4; ++jj) acc[c][jj] += p * w[jj];
        }
    }
    #pragma unroll
    for (int c = 0; c < F / 256; ++c) {
        f32x4 o;
        #pragma unroll
        for (int jj = 0; jj < 4; ++jj) {
            float v = acc[c][jj];
            o[jj] = v > 0.0f ? v : (__expf(v) - 1.0f);
        }
        *(f32x4*)(out + (size_t)row * F + c * 256 + lane * 4) = o;
        if (out16) {
            _Float16 h[4];
            #pragma unroll
            for (int jj = 0; jj < 4; ++jj) h[jj] = (_Float16)o[jj];
            *(__attribute__((ext_vector_type(4))) _Float16*)
                (out16 + (size_t)row * F + c * 256 + lane * 4) =
                *(__attribute__((ext_vector_type(4))) _Float16*)h;
        }
    }
}

// ---------------------------------------------------------------------------
extern "C" void kernel_launch(void* const* d_in, const int* in_sizes, int n_in,
                              void* d_out, int out_size, void* d_ws, size_t ws_size,
                              hipStream_t stream) {
    (void)in_sizes; (void)n_in; (void)out_size; (void)ws_size;
    const float* x   = (const float*)d_in[0];
    const float* adj = (const float*)d_in[1];
    const float* W1  = (const float*)d_in[2];
    const float* a1  = (const float*)d_in[3];
    const float* W2  = (const float*)d_in[4];
    const float* a2  = (const float*)d_in[5];

    float* dec = (float*)d_out;                           // [8192, 512]
    float* enc = dec + (size_t)N_NODES * F_IN;            // [8192, 256]

    int*      cols  = (int*)d_ws;                         // 8192*64
    int*      cnt   = cols + (size_t)N_NODES * MAXDEG;
    float*    sbuf  = (float*)(cnt + N_NODES);
    float*    tbuf  = sbuf + N_NODES;
    float*    Wh1   = tbuf + N_NODES;                     // 8192*256 f32
    float*    Wh2   = Wh1 + (size_t)N_NODES * F_HID;      // 8192*512 f32
    _Float16* x16   = (_Float16*)(Wh2 + (size_t)N_NODES * F_IN);  // 8192*512
    _Float16* enc16 = x16 + (size_t)N_NODES * F_IN;       // 8192*256
    _Float16* W1T   = enc16 + (size_t)N_NODES * F_HID;    // 256*512
    _Float16* W2T   = W1T + (size_t)F_HID * F_IN;         // 512*256

    conv_x16<<<(N_NODES * F_IN / 8) / 256, 256, 0, stream>>>(x, x16);
    conv_WT<<<256, 256, 0, stream>>>(W1, W2, W1T, W2T);
    build_csr<<<N_NODES / 4, 256, 0, stream>>>(adj, cols, cnt);

    // ---- layer 1 (encode): x16 @ W1 -> Wh1 [8192,256] ----
    gemm_f16<<<dim3(F_HID / 64, N_NODES / 64), 256, 0, stream>>>(x16, W1T, Wh1, F_IN, F_HID);
    compute_st<F_HID><<<N_NODES / 4, 256, 0, stream>>>(Wh1, a1, sbuf, tbuf);
    aggregate<F_HID><<<N_NODES / 4, 256, 0, stream>>>(Wh1, cols, cnt, sbuf, tbuf, enc, enc16);

    // ---- layer 2 (decode): enc16 @ W2 -> Wh2 [8192,512] ----
    gemm_f16<<<dim3(F_IN / 64, N_NODES / 64), 256, 0, stream>>>(enc16, W2T, Wh2, F_HID, F_IN);
    compute_st<F_IN><<<N_NODES / 4, 256, 0, stream>>>(Wh2, a2, sbuf, tbuf);
    aggregate<F_IN><<<N_NODES / 4, 256, 0, stream>>>(Wh2, cols, cnt, sbuf, tbuf, dec, (_Float16*)nullptr);
}

// Round 4
// 115.389 us; speedup vs baseline: 2.6148x; 1.2962x over previous
//
#include <hip/hip_runtime.h>
#include <hip/hip_bf16.h>

#define N_NODES 8192
#define F_IN    512
#define F_HID   256
#define ALPHA   0.2f
#define MAXDEG  64

using f32x4 = __attribute__((ext_vector_type(4))) float;
using f16x8 = __attribute__((ext_vector_type(8))) _Float16;
using f16x4 = __attribute__((ext_vector_type(4))) _Float16;

// ---------------------------------------------------------------------------
// W [K][N] f32 -> WT [N][K] fp16, 32x32 LDS tile transpose. Covers both W1,W2.
// ---------------------------------------------------------------------------
__global__ void conv_WT(const float* __restrict__ W1, const float* __restrict__ W2,
                        _Float16* __restrict__ W1T, _Float16* __restrict__ W2T) {
    int t = blockIdx.x;
    const float* W; _Float16* WT; int K, N, kt, nt;
    if (t < 128) { W = W1; WT = W1T; K = 512; N = 256; kt = t & 15; nt = t >> 4; }
    else { t -= 128; W = W2; WT = W2T; K = 256; N = 512; kt = t & 7; nt = t >> 3; }
    __shared__ float Ws[32][33];
    const int tx = threadIdx.x & 31, ty = threadIdx.x >> 5;  // 32 x 8
    #pragma unroll
    for (int i = 0; i < 4; ++i)
        Ws[ty + 8 * i][tx] = W[(size_t)(kt * 32 + ty + 8 * i) * N + nt * 32 + tx];
    __syncthreads();
    #pragma unroll
    for (int i = 0; i < 4; ++i)
        WT[(size_t)(nt * 32 + ty + 8 * i) * K + kt * 32 + tx] = (_Float16)Ws[tx][ty + 8 * i];
}

// ---------------------------------------------------------------------------
// CSR row scan (device body): one wave handles one adjacency row.
// ---------------------------------------------------------------------------
__device__ inline void csr_row(const float* __restrict__ adj, int* __restrict__ cols,
                               int* __restrict__ cnt, int row, int lane) {
    const float4* arow = (const float4*)(adj + (size_t)row * N_NODES);
    int* crow = cols + (size_t)row * MAXDEG;
    int count = 0;
    const unsigned long long mlt = (1ULL << lane) - 1ULL;
    for (int base = 0; base < N_NODES; base += 256) {
        float4 v = arow[(base >> 2) + lane];
        unsigned long long b0 = __ballot(v.x > 0.0f);
        unsigned long long b1 = __ballot(v.y > 0.0f);
        unsigned long long b2 = __ballot(v.z > 0.0f);
        unsigned long long b3 = __ballot(v.w > 0.0f);
        int o = count + __popcll(b0 & mlt) + __popcll(b1 & mlt)
                      + __popcll(b2 & mlt) + __popcll(b3 & mlt);
        int c0 = base + (lane << 2);
        if (v.x > 0.0f) { if (o < MAXDEG) crow[o] = c0;     o++; }
        if (v.y > 0.0f) { if (o < MAXDEG) crow[o] = c0 + 1; o++; }
        if (v.z > 0.0f) { if (o < MAXDEG) crow[o] = c0 + 2; o++; }
        if (v.w > 0.0f) { if (o < MAXDEG) crow[o] = c0 + 3; o++; }
        count += __popcll(b0) + __popcll(b1) + __popcll(b2) + __popcll(b3);
    }
    if (lane == 0) cnt[row] = count > MAXDEG ? MAXDEG : count;
}

// ---------------------------------------------------------------------------
// GEMM1 tile (device body): Wh1[64rows x 64cols] fp16 = x(f32->f16) @ W1T.
// BM=BN=BK=64, 4 waves (2x2), wave tile 32x32, mfma_f32_16x16x32_f16.
// ---------------------------------------------------------------------------
__device__ inline void gemm1_tile(const float* __restrict__ x,
                                  const _Float16* __restrict__ W1T,
                                  _Float16* __restrict__ Wh1,
                                  int brow, int bcol) {
    const int LDT = 72;
    __shared__ _Float16 As[64 * LDT];
    __shared__ _Float16 Bs[64 * LDT];
    const int tid = threadIdx.x;
    const int wid = tid >> 6, lane = tid & 63;
    const int wr = (wid >> 1) * 32, wc = (wid & 1) * 32;
    const int sr = tid >> 3, skg = (tid & 7) * 8;

    f32x4 acc[2][2];
    #pragma unroll
    for (int m = 0; m < 2; ++m)
        #pragma unroll
        for (int n = 0; n < 2; ++n) acc[m][n] = f32x4{0.f, 0.f, 0.f, 0.f};

    for (int k0 = 0; k0 < F_IN; k0 += 64) {
        #pragma unroll
        for (int i = 0; i < 2; ++i) {
            int r = sr + i * 32;
            const float* src = x + (size_t)(brow + r) * F_IN + k0 + skg;
            f32x4 a0 = *(const f32x4*)src;
            f32x4 a1 = *(const f32x4*)(src + 4);
            f16x8 av;
            #pragma unroll
            for (int j = 0; j < 4; ++j) { av[j] = (_Float16)a0[j]; av[4 + j] = (_Float16)a1[j]; }
            *(f16x8*)&As[r * LDT + skg] = av;
            *(f16x8*)&Bs[r * LDT + skg] = *(const f16x8*)&W1T[(size_t)(bcol + r) * F_IN + k0 + skg];
        }
        __syncthreads();
        #pragma unroll
        for (int ks = 0; ks < 2; ++ks) {
            const int kb = ks * 32 + (lane >> 4) * 8;
            f16x8 af[2], bfr[2];
            #pragma unroll
            for (int m = 0; m < 2; ++m)
                af[m] = *(const f16x8*)&As[(wr + m * 16 + (lane & 15)) * LDT + kb];
            #pragma unroll
            for (int n = 0; n < 2; ++n)
                bfr[n] = *(const f16x8*)&Bs[(wc + n * 16 + (lane & 15)) * LDT + kb];
            #pragma unroll
            for (int m = 0; m < 2; ++m)
                #pragma unroll
                for (int n = 0; n < 2; ++n)
                    acc[m][n] = __builtin_amdgcn_mfma_f32_16x16x32_f16(
                        af[m], bfr[n], acc[m][n], 0, 0, 0);
        }
        __syncthreads();
    }
    #pragma unroll
    for (int m = 0; m < 2; ++m)
        #pragma unroll
        for (int n = 0; n < 2; ++n) {
            int row = brow + wr + m * 16 + ((lane >> 4) << 2);
            int col = bcol + wc + n * 16 + (lane & 15);
            #pragma unroll
            for (int j = 0; j < 4; ++j)
                Wh1[(size_t)(row + j) * F_HID + col] = (_Float16)acc[m][n][j];
        }
}

// ---------------------------------------------------------------------------
// Merged kernel: csr scan (HBM-bound) co-scheduled with GEMM1 (MFMA-bound).
// bid%5==0 -> gemm tile; else csr 4-row block. Independent work, one launch.
// ---------------------------------------------------------------------------
__global__ __launch_bounds__(256)
void csr_and_gemm1(const float* __restrict__ adj, int* __restrict__ cols,
                   int* __restrict__ cnt, const float* __restrict__ x,
                   const _Float16* __restrict__ W1T, _Float16* __restrict__ Wh1) {
    const int bid = blockIdx.x;
    const int g = bid / 5, r = bid % 5;
    if (r == 0) {
        gemm1_tile(x, W1T, Wh1, (g >> 2) * 64, (g & 3) * 64);
    } else {
        const int cb = g * 4 + (r - 1);                 // [0, 2048)
        const int row = cb * 4 + (threadIdx.x >> 6);    // 4 waves -> 4 rows
        csr_row(adj, cols, cnt, row, threadIdx.x & 63);
    }
}

// ---------------------------------------------------------------------------
// GEMM2: Wh2[8192,512] fp16 = enc16[8192,256] @ W2T[512][256].
// ---------------------------------------------------------------------------
__global__ __launch_bounds__(256)
void gemm2_f16(const _Float16* __restrict__ A, const _Float16* __restrict__ BT,
               _Float16* __restrict__ C) {
    const int LDT = 72;
    __shared__ _Float16 As[64 * LDT];
    __shared__ _Float16 Bs[64 * LDT];
    const int tid = threadIdx.x;
    const int wid = tid >> 6, lane = tid & 63;
    const int brow = (blockIdx.x >> 3) * 64;
    const int bcol = (blockIdx.x & 7) * 64;
    const int wr = (wid >> 1) * 32, wc = (wid & 1) * 32;
    const int sr = tid >> 3, skg = (tid & 7) * 8;

    f32x4 acc[2][2];
    #pragma unroll
    for (int m = 0; m < 2; ++m)
        #pragma unroll
        for (int n = 0; n < 2; ++n) acc[m][n] = f32x4{0.f, 0.f, 0.f, 0.f};

    for (int k0 = 0; k0 < F_HID; k0 += 64) {
        #pragma unroll
        for (int i = 0; i < 2; ++i) {
            int r = sr + i * 32;
            *(f16x8*)&As[r * LDT + skg] = *(const f16x8*)&A[(size_t)(brow + r) * F_HID + k0 + skg];
            *(f16x8*)&Bs[r * LDT + skg] = *(const f16x8*)&BT[(size_t)(bcol + r) * F_HID + k0 + skg];
        }
        __syncthreads();
        #pragma unroll
        for (int ks = 0; ks < 2; ++ks) {
            const int kb = ks * 32 + (lane >> 4) * 8;
            f16x8 af[2], bfr[2];
            #pragma unroll
            for (int m = 0; m < 2; ++m)
                af[m] = *(const f16x8*)&As[(wr + m * 16 + (lane & 15)) * LDT + kb];
            #pragma unroll
            for (int n = 0; n < 2; ++n)
                bfr[n] = *(const f16x8*)&Bs[(wc + n * 16 + (lane & 15)) * LDT + kb];
            #pragma unroll
            for (int m = 0; m < 2; ++m)
                #pragma unroll
                for (int n = 0; n < 2; ++n)
                    acc[m][n] = __builtin_amdgcn_mfma_f32_16x16x32_f16(
                        af[m], bfr[n], acc[m][n], 0, 0, 0);
        }
        __syncthreads();
    }
    #pragma unroll
    for (int m = 0; m < 2; ++m)
        #pragma unroll
        for (int n = 0; n < 2; ++n) {
            int row = brow + wr + m * 16 + ((lane >> 4) << 2);
            int col = bcol + wc + n * 16 + (lane & 15);
            #pragma unroll
            for (int j = 0; j < 4; ++j)
                C[(size_t)(row + j) * F_IN + col] = (_Float16)acc[m][n][j];
        }
}

// ---------------------------------------------------------------------------
// s[i] = Wh[i,:].a[0:F], t[i] = Wh[i,:].a[F:2F]. Wave per row, fp16 Wh.
// ---------------------------------------------------------------------------
template<int F>
__global__ void compute_st16(const _Float16* __restrict__ Wh, const float* __restrict__ a,
                             float* __restrict__ s, float* __restrict__ t) {
    const int EL = F / 64;
    const int lane = threadIdx.x & 63;
    const int row = blockIdx.x * 4 + (threadIdx.x >> 6);
    const _Float16* wr = Wh + (size_t)row * F + lane * EL;
    float ss = 0.f, tt = 0.f;
    #pragma unroll
    for (int c = 0; c < EL / 4; ++c) {
        f16x4 w = *(const f16x4*)(wr + c * 4);
        f32x4 a0 = *(const f32x4*)(a + lane * EL + c * 4);
        f32x4 a1 = *(const f32x4*)(a + F + lane * EL + c * 4);
        #pragma unroll
        for (int j = 0; j < 4; ++j) {
            float v = (float)w[j];
            ss += v * a0[j];
            tt += v * a1[j];
        }
    }
    #pragma unroll
    for (int off = 32; off > 0; off >>= 1) {
        ss += __shfl_xor(ss, off);
        tt += __shfl_xor(tt, off);
    }
    if (lane == 0) { s[row] = ss; t[row] = tt; }
}

// ---------------------------------------------------------------------------
// Masked softmax over neighbors + aggregate + ELU. Wave per row, fp16 gathers.
// Optionally emits fp16 copy of the output (next layer's GEMM input).
// ---------------------------------------------------------------------------
template<int F>
__global__ void aggregate16(const _Float16* __restrict__ Wh,
                            const int* __restrict__ cols, const int* __restrict__ cnt,
                            const float* __restrict__ s, const float* __restrict__ t,
                            float* __restrict__ out, _Float16* __restrict__ out16) {
    const int EL = F / 64;
    const int wid = threadIdx.x >> 6, lane = threadIdx.x & 63;
    const int row = blockIdx.x * 4 + wid;
    const int deg = cnt[row];
    __shared__ float pS[4][64];
    __shared__ int jS[4][64];
    int j = 0;
    float ev = -1e30f;
    if (lane < deg) {
        j = cols[(size_t)row * MAXDEG + lane];
        float z = s[row] + t[j];
        ev = z > 0.0f ? z : ALPHA * z;
    }
    float m = ev;
    #pragma unroll
    for (int off = 32; off > 0; off >>= 1) m = fmaxf(m, __shfl_xor(m, off));
    float ex = (lane < deg) ? __expf(ev - m) : 0.0f;
    float sum = ex;
    #pragma unroll
    for (int off = 32; off > 0; off >>= 1) sum += __shfl_xor(sum, off);
    pS[wid][lane] = ex / sum;
    jS[wid][lane] = j;
    __syncthreads();

    float acc[EL] = {};
    #pragma unroll 2
    for (int d = 0; d < deg; ++d) {
        float p = pS[wid][d];
        const _Float16* wr = Wh + (size_t)jS[wid][d] * F + lane * EL;
        if constexpr (EL == 8) {
            f16x8 w = *(const f16x8*)wr;
            #pragma unroll
            for (int jj = 0; jj < 8; ++jj) acc[jj] += p * (float)w[jj];
        } else {
            f16x4 w = *(const f16x4*)wr;
            #pragma unroll
            for (int jj = 0; jj < 4; ++jj) acc[jj] += p * (float)w[jj];
        }
    }
    #pragma unroll
    for (int c = 0; c < EL / 4; ++c) {
        f32x4 o; f16x4 h;
        #pragma unroll
        for (int jj = 0; jj < 4; ++jj) {
            float v = acc[c * 4 + jj];
            float e = v > 0.0f ? v : (__expf(v) - 1.0f);
            o[jj] = e; h[jj] = (_Float16)e;
        }
        *(f32x4*)(out + (size_t)row * F + lane * EL + c * 4) = o;
        if (out16)
            *(f16x4*)(out16 + (size_t)row * F + lane * EL + c * 4) = h;
    }
}

// ---------------------------------------------------------------------------
extern "C" void kernel_launch(void* const* d_in, const int* in_sizes, int n_in,
                              void* d_out, int out_size, void* d_ws, size_t ws_size,
                              hipStream_t stream) {
    (void)in_sizes; (void)n_in; (void)out_size; (void)ws_size;
    const float* x   = (const float*)d_in[0];
    const float* adj = (const float*)d_in[1];
    const float* W1  = (const float*)d_in[2];
    const float* a1  = (const float*)d_in[3];
    const float* W2  = (const float*)d_in[4];
    const float* a2  = (const float*)d_in[5];

    float* dec = (float*)d_out;                           // [8192, 512] f32
    float* enc = dec + (size_t)N_NODES * F_IN;            // [8192, 256] f32

    int*      cols  = (int*)d_ws;                         // 8192*64
    int*      cnt   = cols + (size_t)N_NODES * MAXDEG;    // 8192
    float*    sbuf  = (float*)(cnt + N_NODES);            // 8192
    float*    tbuf  = sbuf + N_NODES;                     // 8192
    _Float16* Wh1   = (_Float16*)(tbuf + N_NODES);        // 8192*256 fp16
    _Float16* Wh2   = Wh1 + (size_t)N_NODES * F_HID;      // 8192*512 fp16
    _Float16* enc16 = Wh2 + (size_t)N_NODES * F_IN;       // 8192*256 fp16
    _Float16* W1T   = enc16 + (size_t)N_NODES * F_HID;    // 256*512 fp16
    _Float16* W2T   = W1T + (size_t)F_HID * F_IN;         // 512*256 fp16

    // W transposes (must precede gemm1 in merged kernel)
    conv_WT<<<256, 256, 0, stream>>>(W1, W2, W1T, W2T);

    // csr scan (HBM) overlapped with layer-1 GEMM (MFMA)
    csr_and_gemm1<<<2560, 256, 0, stream>>>(adj, cols, cnt, x, W1T, Wh1);

    // ---- layer 1 attention ----
    compute_st16<F_HID><<<N_NODES / 4, 256, 0, stream>>>(Wh1, a1, sbuf, tbuf);
    aggregate16<F_HID><<<N_NODES / 4, 256, 0, stream>>>(Wh1, cols, cnt, sbuf, tbuf, enc, enc16);

    // ---- layer 2 ----
    gemm2_f16<<<1024, 256, 0, stream>>>(enc16, W2T, Wh2);
    compute_st16<F_IN><<<N_NODES / 4, 256, 0, stream>>>(Wh2, a2, sbuf, tbuf);
    aggregate16<F_IN><<<N_NODES / 4, 256, 0, stream>>>(Wh2, cols, cnt, sbuf, tbuf, dec, (_Float16*)nullptr);
}

// Round 5
// 113.052 us; speedup vs baseline: 2.6689x; 1.0207x over previous
//
#include <hip/hip_runtime.h>
#include <hip/hip_bf16.h>

#define N_NODES 8192
#define F_IN    512
#define F_HID   256
#define ALPHA   0.2f
#define MAXDEG  64

using f32x4 = __attribute__((ext_vector_type(4))) float;
using f16x8 = __attribute__((ext_vector_type(8))) _Float16;
using f16x4 = __attribute__((ext_vector_type(4))) _Float16;

// ---------------------------------------------------------------------------
// Kernel 1: W f32 -> WT fp16 (both layers) + zero the 4 s/t accumulators.
// ---------------------------------------------------------------------------
__global__ void conv_WT(const float* __restrict__ W1, const float* __restrict__ W2,
                        _Float16* __restrict__ W1T, _Float16* __restrict__ W2T,
                        float* __restrict__ stz) {
    // zero s1,t1,s2,t2 (4 * 8192 floats)
    int gid = blockIdx.x * blockDim.x + threadIdx.x;
    if (gid < 4 * N_NODES) stz[gid] = 0.0f;

    int t = blockIdx.x;
    const float* W; _Float16* WT; int K, N, kt, nt;
    if (t < 128) { W = W1; WT = W1T; K = 512; N = 256; kt = t & 15; nt = t >> 4; }
    else { t -= 128; W = W2; WT = W2T; K = 256; N = 512; kt = t & 7; nt = t >> 3; }
    __shared__ float Ws[32][33];
    const int tx = threadIdx.x & 31, ty = threadIdx.x >> 5;  // 32 x 8
    #pragma unroll
    for (int i = 0; i < 4; ++i)
        Ws[ty + 8 * i][tx] = W[(size_t)(kt * 32 + ty + 8 * i) * N + nt * 32 + tx];
    __syncthreads();
    #pragma unroll
    for (int i = 0; i < 4; ++i)
        WT[(size_t)(nt * 32 + ty + 8 * i) * K + kt * 32 + tx] = (_Float16)Ws[tx][ty + 8 * i];
}

// ---------------------------------------------------------------------------
// CSR row scan (device body): one wave per adjacency row.
// ---------------------------------------------------------------------------
__device__ inline void csr_row(const float* __restrict__ adj, int* __restrict__ cols,
                               int* __restrict__ cnt, int row, int lane) {
    const float4* arow = (const float4*)(adj + (size_t)row * N_NODES);
    int* crow = cols + (size_t)row * MAXDEG;
    int count = 0;
    const unsigned long long mlt = (1ULL << lane) - 1ULL;
    for (int base = 0; base < N_NODES; base += 256) {
        float4 v = arow[(base >> 2) + lane];
        unsigned long long b0 = __ballot(v.x > 0.0f);
        unsigned long long b1 = __ballot(v.y > 0.0f);
        unsigned long long b2 = __ballot(v.z > 0.0f);
        unsigned long long b3 = __ballot(v.w > 0.0f);
        int o = count + __popcll(b0 & mlt) + __popcll(b1 & mlt)
                      + __popcll(b2 & mlt) + __popcll(b3 & mlt);
        int c0 = base + (lane << 2);
        if (v.x > 0.0f) { if (o < MAXDEG) crow[o] = c0;     o++; }
        if (v.y > 0.0f) { if (o < MAXDEG) crow[o] = c0 + 1; o++; }
        if (v.z > 0.0f) { if (o < MAXDEG) crow[o] = c0 + 2; o++; }
        if (v.w > 0.0f) { if (o < MAXDEG) crow[o] = c0 + 3; o++; }
        count += __popcll(b0) + __popcll(b1) + __popcll(b2) + __popcll(b3);
    }
    if (lane == 0) cnt[row] = count > MAXDEG ? MAXDEG : count;
}

// ---------------------------------------------------------------------------
// GEMM1 tile: Wh1[64x64] fp16 = x(f32->f16) @ W1T; epilogue adds this tile's
// contribution to s1/t1 (16-lane reduce + atomicAdd).
// ---------------------------------------------------------------------------
__device__ inline void gemm1_tile(const float* __restrict__ x,
                                  const _Float16* __restrict__ W1T,
                                  _Float16* __restrict__ Wh1,
                                  const float* __restrict__ a1,
                                  float* __restrict__ s1, float* __restrict__ t1,
                                  int brow, int bcol) {
    const int LDT = 72;
    __shared__ _Float16 As[64 * LDT];
    __shared__ _Float16 Bs[64 * LDT];
    const int tid = threadIdx.x;
    const int wid = tid >> 6, lane = tid & 63;
    const int wr = (wid >> 1) * 32, wc = (wid & 1) * 32;
    const int sr = tid >> 3, skg = (tid & 7) * 8;

    f32x4 acc[2][2];
    #pragma unroll
    for (int m = 0; m < 2; ++m)
        #pragma unroll
        for (int n = 0; n < 2; ++n) acc[m][n] = f32x4{0.f, 0.f, 0.f, 0.f};

    for (int k0 = 0; k0 < F_IN; k0 += 64) {
        #pragma unroll
        for (int i = 0; i < 2; ++i) {
            int r = sr + i * 32;
            const float* src = x + (size_t)(brow + r) * F_IN + k0 + skg;
            f32x4 a0 = *(const f32x4*)src;
            f32x4 a1v = *(const f32x4*)(src + 4);
            f16x8 av;
            #pragma unroll
            for (int j = 0; j < 4; ++j) { av[j] = (_Float16)a0[j]; av[4 + j] = (_Float16)a1v[j]; }
            *(f16x8*)&As[r * LDT + skg] = av;
            *(f16x8*)&Bs[r * LDT + skg] = *(const f16x8*)&W1T[(size_t)(bcol + r) * F_IN + k0 + skg];
        }
        __syncthreads();
        #pragma unroll
        for (int ks = 0; ks < 2; ++ks) {
            const int kb = ks * 32 + (lane >> 4) * 8;
            f16x8 af[2], bfr[2];
            #pragma unroll
            for (int m = 0; m < 2; ++m)
                af[m] = *(const f16x8*)&As[(wr + m * 16 + (lane & 15)) * LDT + kb];
            #pragma unroll
            for (int n = 0; n < 2; ++n)
                bfr[n] = *(const f16x8*)&Bs[(wc + n * 16 + (lane & 15)) * LDT + kb];
            #pragma unroll
            for (int m = 0; m < 2; ++m)
                #pragma unroll
                for (int n = 0; n < 2; ++n)
                    acc[m][n] = __builtin_amdgcn_mfma_f32_16x16x32_f16(
                        af[m], bfr[n], acc[m][n], 0, 0, 0);
        }
        __syncthreads();
    }
    // a-vector slices for this lane's two columns
    const int c0 = bcol + wc + (lane & 15);
    float as0 = a1[c0],      as1 = a1[c0 + 16];
    float at0 = a1[F_HID + c0], at1 = a1[F_HID + c0 + 16];
    #pragma unroll
    for (int m = 0; m < 2; ++m) {
        #pragma unroll
        for (int j = 0; j < 4; ++j) {
            float vs = acc[m][0][j] * as0 + acc[m][1][j] * as1;
            float vt = acc[m][0][j] * at0 + acc[m][1][j] * at1;
            #pragma unroll
            for (int off = 1; off < 16; off <<= 1) {
                vs += __shfl_xor(vs, off);
                vt += __shfl_xor(vt, off);
            }
            if ((lane & 15) == 0) {
                int row = brow + wr + m * 16 + ((lane >> 4) << 2) + j;
                atomicAdd(s1 + row, vs);
                atomicAdd(t1 + row, vt);
            }
        }
        #pragma unroll
        for (int n = 0; n < 2; ++n) {
            int row = brow + wr + m * 16 + ((lane >> 4) << 2);
            int col = bcol + wc + n * 16 + (lane & 15);
            #pragma unroll
            for (int j = 0; j < 4; ++j)
                Wh1[(size_t)(row + j) * F_HID + col] = (_Float16)acc[m][n][j];
        }
    }
}

// ---------------------------------------------------------------------------
// Merged: csr scan (HBM-bound) co-scheduled with GEMM1+st1 (MFMA-bound).
// ---------------------------------------------------------------------------
__global__ __launch_bounds__(256)
void csr_and_gemm1(const float* __restrict__ adj, int* __restrict__ cols,
                   int* __restrict__ cnt, const float* __restrict__ x,
                   const _Float16* __restrict__ W1T, _Float16* __restrict__ Wh1,
                   const float* __restrict__ a1,
                   float* __restrict__ s1, float* __restrict__ t1) {
    const int bid = blockIdx.x;
    const int g = bid / 5, r = bid % 5;
    if (r == 0) {
        gemm1_tile(x, W1T, Wh1, a1, s1, t1, (g >> 2) * 64, (g & 3) * 64);
    } else {
        const int cb = g * 4 + (r - 1);                 // [0, 2048)
        const int row = cb * 4 + (threadIdx.x >> 6);
        csr_row(adj, cols, cnt, row, threadIdx.x & 63);
    }
}

// ---------------------------------------------------------------------------
// GEMM2: Wh2[8192,512] fp16 = enc16 @ W2T, BM=128 BN=64, 4 waves (2x2),
// wave tile 64x32; epilogue adds to s2/t2.
// ---------------------------------------------------------------------------
__global__ __launch_bounds__(256)
void gemm2_f16(const _Float16* __restrict__ A, const _Float16* __restrict__ BT,
               _Float16* __restrict__ C, const float* __restrict__ a2,
               float* __restrict__ s2, float* __restrict__ t2) {
    const int LDT = 72;
    __shared__ _Float16 As[128 * LDT];
    __shared__ _Float16 Bs[64 * LDT];
    const int tid = threadIdx.x;
    const int wid = tid >> 6, lane = tid & 63;
    const int brow = (blockIdx.x >> 3) * 128;
    const int bcol = (blockIdx.x & 7) * 64;
    const int wr = (wid >> 1) * 64, wc = (wid & 1) * 32;
    const int sr = tid >> 3, skg = (tid & 7) * 8;

    f32x4 acc[4][2];
    #pragma unroll
    for (int m = 0; m < 4; ++m)
        #pragma unroll
        for (int n = 0; n < 2; ++n) acc[m][n] = f32x4{0.f, 0.f, 0.f, 0.f};

    for (int k0 = 0; k0 < F_HID; k0 += 64) {
        #pragma unroll
        for (int i = 0; i < 4; ++i) {
            int r = sr + i * 32;
            *(f16x8*)&As[r * LDT + skg] = *(const f16x8*)&A[(size_t)(brow + r) * F_HID + k0 + skg];
            if (i < 2)
                *(f16x8*)&Bs[(r & 63) * LDT + skg] =
                    *(const f16x8*)&BT[(size_t)(bcol + (r & 63)) * F_HID + k0 + skg];
        }
        __syncthreads();
        #pragma unroll
        for (int ks = 0; ks < 2; ++ks) {
            const int kb = ks * 32 + (lane >> 4) * 8;
            f16x8 af[4], bfr[2];
            #pragma unroll
            for (int m = 0; m < 4; ++m)
                af[m] = *(const f16x8*)&As[(wr + m * 16 + (lane & 15)) * LDT + kb];
            #pragma unroll
            for (int n = 0; n < 2; ++n)
                bfr[n] = *(const f16x8*)&Bs[(wc + n * 16 + (lane & 15)) * LDT + kb];
            #pragma unroll
            for (int m = 0; m < 4; ++m)
                #pragma unroll
                for (int n = 0; n < 2; ++n)
                    acc[m][n] = __builtin_amdgcn_mfma_f32_16x16x32_f16(
                        af[m], bfr[n], acc[m][n], 0, 0, 0);
        }
        __syncthreads();
    }
    const int c0 = bcol + wc + (lane & 15);
    float as0 = a2[c0],        as1 = a2[c0 + 16];
    float at0 = a2[F_IN + c0], at1 = a2[F_IN + c0 + 16];
    #pragma unroll
    for (int m = 0; m < 4; ++m) {
        #pragma unroll
        for (int j = 0; j < 4; ++j) {
            float vs = acc[m][0][j] * as0 + acc[m][1][j] * as1;
            float vt = acc[m][0][j] * at0 + acc[m][1][j] * at1;
            #pragma unroll
            for (int off = 1; off < 16; off <<= 1) {
                vs += __shfl_xor(vs, off);
                vt += __shfl_xor(vt, off);
            }
            if ((lane & 15) == 0) {
                int row = brow + wr + m * 16 + ((lane >> 4) << 2) + j;
                atomicAdd(s2 + row, vs);
                atomicAdd(t2 + row, vt);
            }
        }
        #pragma unroll
        for (int n = 0; n < 2; ++n) {
            int row = brow + wr + m * 16 + ((lane >> 4) << 2);
            int col = bcol + wc + n * 16 + (lane & 15);
            #pragma unroll
            for (int j = 0; j < 4; ++j)
                C[(size_t)(row + j) * F_IN + col] = (_Float16)acc[m][n][j];
        }
    }
}

// ---------------------------------------------------------------------------
// Masked softmax + aggregate + ELU. Wave per row, fp16 gathers, unroll-4.
// ---------------------------------------------------------------------------
template<int F>
__global__ void aggregate16(const _Float16* __restrict__ Wh,
                            const int* __restrict__ cols, const int* __restrict__ cnt,
                            const float* __restrict__ s, const float* __restrict__ t,
                            float* __restrict__ out, _Float16* __restrict__ out16) {
    const int EL = F / 64;
    const int wid = threadIdx.x >> 6, lane = threadIdx.x & 63;
    const int row = blockIdx.x * 4 + wid;
    const int deg = cnt[row];
    __shared__ float pS[4][64];
    __shared__ int jS[4][64];
    int j = 0;
    float ev = -1e30f;
    if (lane < deg) {
        j = cols[(size_t)row * MAXDEG + lane];
        float z = s[row] + t[j];
        ev = z > 0.0f ? z : ALPHA * z;
    }
    float m = ev;
    #pragma unroll
    for (int off = 32; off > 0; off >>= 1) m = fmaxf(m, __shfl_xor(m, off));
    float ex = (lane < deg) ? __expf(ev - m) : 0.0f;
    float sum = ex;
    #pragma unroll
    for (int off = 32; off > 0; off >>= 1) sum += __shfl_xor(sum, off);
    pS[wid][lane] = ex / sum;
    jS[wid][lane] = j;
    __syncthreads();

    float acc[EL] = {};
    const size_t lo = (size_t)lane * EL;
    int d = 0;
    for (; d + 4 <= deg; d += 4) {
        float p0 = pS[wid][d],     p1 = pS[wid][d + 1];
        float p2 = pS[wid][d + 2], p3 = pS[wid][d + 3];
        const _Float16* w0 = Wh + (size_t)jS[wid][d] * F + lo;
        const _Float16* w1 = Wh + (size_t)jS[wid][d + 1] * F + lo;
        const _Float16* w2 = Wh + (size_t)jS[wid][d + 2] * F + lo;
        const _Float16* w3 = Wh + (size_t)jS[wid][d + 3] * F + lo;
        if constexpr (EL == 8) {
            f16x8 v0 = *(const f16x8*)w0, v1 = *(const f16x8*)w1;
            f16x8 v2 = *(const f16x8*)w2, v3 = *(const f16x8*)w3;
            #pragma unroll
            for (int jj = 0; jj < 8; ++jj)
                acc[jj] += p0 * (float)v0[jj] + p1 * (float)v1[jj]
                         + p2 * (float)v2[jj] + p3 * (float)v3[jj];
        } else {
            f16x4 v0 = *(const f16x4*)w0, v1 = *(const f16x4*)w1;
            f16x4 v2 = *(const f16x4*)w2, v3 = *(const f16x4*)w3;
            #pragma unroll
            for (int jj = 0; jj < 4; ++jj)
                acc[jj] += p0 * (float)v0[jj] + p1 * (float)v1[jj]
                         + p2 * (float)v2[jj] + p3 * (float)v3[jj];
        }
    }
    for (; d < deg; ++d) {
        float p = pS[wid][d];
        const _Float16* wr = Wh + (size_t)jS[wid][d] * F + lo;
        if constexpr (EL == 8) {
            f16x8 w = *(const f16x8*)wr;
            #pragma unroll
            for (int jj = 0; jj < 8; ++jj) acc[jj] += p * (float)w[jj];
        } else {
            f16x4 w = *(const f16x4*)wr;
            #pragma unroll
            for (int jj = 0; jj < 4; ++jj) acc[jj] += p * (float)w[jj];
        }
    }
    #pragma unroll
    for (int c = 0; c < EL / 4; ++c) {
        f32x4 o; f16x4 h;
        #pragma unroll
        for (int jj = 0; jj < 4; ++jj) {
            float v = acc[c * 4 + jj];
            float e = v > 0.0f ? v : (__expf(v) - 1.0f);
            o[jj] = e; h[jj] = (_Float16)e;
        }
        *(f32x4*)(out + (size_t)row * F + lo + c * 4) = o;
        if (out16)
            *(f16x4*)(out16 + (size_t)row * F + lo + c * 4) = h;
    }
}

// ---------------------------------------------------------------------------
extern "C" void kernel_launch(void* const* d_in, const int* in_sizes, int n_in,
                              void* d_out, int out_size, void* d_ws, size_t ws_size,
                              hipStream_t stream) {
    (void)in_sizes; (void)n_in; (void)out_size; (void)ws_size;
    const float* x   = (const float*)d_in[0];
    const float* adj = (const float*)d_in[1];
    const float* W1  = (const float*)d_in[2];
    const float* a1  = (const float*)d_in[3];
    const float* W2  = (const float*)d_in[4];
    const float* a2  = (const float*)d_in[5];

    float* dec = (float*)d_out;                           // [8192, 512] f32
    float* enc = dec + (size_t)N_NODES * F_IN;            // [8192, 256] f32

    int*      cols  = (int*)d_ws;                         // 8192*64
    int*      cnt   = cols + (size_t)N_NODES * MAXDEG;    // 8192
    float*    s1    = (float*)(cnt + N_NODES);            // 8192
    float*    t1    = s1 + N_NODES;                       // 8192
    float*    s2    = t1 + N_NODES;                       // 8192
    float*    t2    = s2 + N_NODES;                       // 8192
    _Float16* Wh1   = (_Float16*)(t2 + N_NODES);          // 8192*256 fp16
    _Float16* Wh2   = Wh1 + (size_t)N_NODES * F_HID;      // 8192*512 fp16
    _Float16* enc16 = Wh2 + (size_t)N_NODES * F_IN;       // 8192*256 fp16
    _Float16* W1T   = enc16 + (size_t)N_NODES * F_HID;    // 256*512 fp16
    _Float16* W2T   = W1T + (size_t)F_HID * F_IN;         // 512*256 fp16

    // 1. W transposes + zero s/t accumulators
    conv_WT<<<256, 256, 0, stream>>>(W1, W2, W1T, W2T, s1);

    // 2. csr scan (HBM) overlapped with layer-1 GEMM + st1 epilogue (MFMA)
    csr_and_gemm1<<<2560, 256, 0, stream>>>(adj, cols, cnt, x, W1T, Wh1, a1, s1, t1);

    // 3. layer-1 attention
    aggregate16<F_HID><<<N_NODES / 4, 256, 0, stream>>>(Wh1, cols, cnt, s1, t1, enc, enc16);

    // 4. layer-2 GEMM + st2 epilogue
    gemm2_f16<<<512, 256, 0, stream>>>(enc16, W2T, Wh2, a2, s2, t2);

    // 5. layer-2 attention
    aggregate16<F_IN><<<N_NODES / 4, 256, 0, stream>>>(Wh2, cols, cnt, s2, t2, dec, (_Float16*)nullptr);
}